// Round 1
// baseline (90.518 us; speedup 1.0000x reference)
//
#include <hip/hip_runtime.h>
#include <math.h>

#define NG   4096
#define HH   128
#define WW   128
#define NPIX (HH*WW)
#define EPSF 1e-6f
#define CHUNK 128
#define NCH  (NG/CHUNK)     // 32
#define PXB  (NPIX/256)     // 64

#if __has_builtin(__builtin_amdgcn_exp2f)
#define EXP2F(x) __builtin_amdgcn_exp2f(x)
#else
#define EXP2F(x) exp2f(x)
#endif

// Per-gaussian preprocess: quat -> R4 -> cov4D -> conditioned 3D -> view -> 2D conic.
// Emits 8 floats/gaussian: mux, muy, A, B, C, c0, pad, pad
// where patch(px,py) = exp2(A*dx*dx + B*dx*dy + C*dy*dy + c0), dx=px-mux, dy=py-muy.
__global__ __launch_bounds__(256) void prep_kernel(
    const float* __restrict__ means, const float* __restrict__ raw_scales,
    const float* __restrict__ rotors, const float* __restrict__ tp,
    const float* __restrict__ ap, float* __restrict__ params)
{
    int i = blockIdx.x * 256 + threadIdx.x;
    if (i >= NG) return;
    float t = tp[0], angle = ap[0];

    float r0 = rotors[i*8+0], r1 = rotors[i*8+1], r2 = rotors[i*8+2], r3 = rotors[i*8+3];
    float r4 = rotors[i*8+4], r5 = rotors[i*8+5], r6 = rotors[i*8+6], r7 = rotors[i*8+7];

    // q1 = normalize([r0, r4, r5, r6])
    float w1 = r0, x1 = r4, y1 = r5, z1 = r6;
    float n1 = sqrtf(w1*w1 + x1*x1 + y1*y1 + z1*z1);
    n1 = fmaxf(n1, 1e-12f);
    w1 /= n1; x1 /= n1; y1 /= n1; z1 /= n1;
    // q2 = normalize([r7, -r1, -r2, -r3])
    float w2 = r7, x2 = -r1, y2 = -r2, z2 = -r3;
    float n2 = sqrtf(w2*w2 + x2*x2 + y2*y2 + z2*z2);
    n2 = fmaxf(n2, 1e-12f);
    w2 /= n2; x2 /= n2; y2 /= n2; z2 /= n2;

    float L[4][4]  = {{w1,-x1,-y1,-z1},{x1,w1,-z1,y1},{y1,z1,w1,-x1},{z1,-y1,x1,w1}};
    float Rm[4][4] = {{w2, x2, y2, z2},{-x2,w2,z2,-y2},{-y2,-z2,w2,x2},{-z2,y2,-x2,w2}};

    float R4[4][4];
    #pragma unroll
    for (int a = 0; a < 4; ++a)
        #pragma unroll
        for (int b = 0; b < 4; ++b)
            R4[a][b] = L[a][0]*Rm[0][b] + L[a][1]*Rm[1][b] + L[a][2]*Rm[2][b] + L[a][3]*Rm[3][b];

    float s2[4];
    #pragma unroll
    for (int j = 0; j < 4; ++j) {
        float e = expf(raw_scales[i*4+j]);
        s2[j] = e * e;
    }

    // cov4D[a][b] = sum_j R4[a][j]*s2[j]*R4[b][j]  (symmetric)
    float cov[4][4];
    #pragma unroll
    for (int a = 0; a < 4; ++a)
        #pragma unroll
        for (int b = a; b < 4; ++b) {
            float s = R4[a][0]*s2[0]*R4[b][0] + R4[a][1]*s2[1]*R4[b][1]
                    + R4[a][2]*s2[2]*R4[b][2] + R4[a][3]*s2[3]*R4[b][3];
            cov[a][b] = s; cov[b][a] = s;
        }

    float Wm   = fmaxf(cov[3][3], EPSF);
    float invW = 1.0f / Wm;
    float V0 = cov[0][3], V1 = cov[1][3], V2 = cov[2][3];
    float td = t - means[i*4+3];

    float mu0 = means[i*4+0] + V0 * td * invW;
    float mu1 = means[i*4+1] + V1 * td * invW;
    float mu2 = means[i*4+2] + V2 * td * invW;

    float ca = cosf(angle), sa = sinf(angle);
    float mvx = ca*mu0 + sa*mu2;   // view row0 = (c,0,s)
    float mvy = mu1;               // view row1 = (0,1,0)

    // cov3D = U - V V^T / Wm
    float C00 = cov[0][0] - V0*V0*invW;
    float C01 = cov[0][1] - V0*V1*invW;
    float C02 = cov[0][2] - V0*V2*invW;
    float C11 = cov[1][1] - V1*V1*invW;
    float C12 = cov[1][2] - V1*V2*invW;
    float C22 = cov[2][2] - V2*V2*invW;

    // cov3D_view projected to the 2 screen axes
    float cv00 = ca*ca*C00 + 2.f*ca*sa*C02 + sa*sa*C22;
    float cv01 = ca*C01 + sa*C12;
    float cv11 = C11;

    const float Ksc = 31.75f;          // (W-1)/2 * ZOOM
    const float K2  = Ksc * Ksc;
    float a = K2*cv00 + EPSF;
    float b = K2*cv01;
    float d = K2*cv11 + EPSF;
    float det = a*d - b*b;
    float invdet = 1.0f / det;

    const float L2E = 1.4426950408889634f;
    float A  = -0.5f * d * invdet * L2E;
    float B  =         b * invdet * L2E;
    float C  = -0.5f * a * invdet * L2E;
    float c0 = -0.5f * invW * td * td * L2E;   // time weight folded in

    float mux = Ksc*mvx + 63.5f;
    float muy = Ksc*mvy + 63.5f;

    float* p = params + i*8;
    p[0] = mux; p[1] = muy; p[2] = A; p[3] = B; p[4] = C; p[5] = c0;
    p[6] = 0.f; p[7] = 0.f;
}

// Rasterize: one thread per pixel, each block handles one chunk of gaussians.
__global__ __launch_bounds__(256) void accum_kernel(
    const float* __restrict__ params, float* __restrict__ acc)
{
    __shared__ float sp[CHUNK][8];
    int tid = threadIdx.x;
    int pb  = blockIdx.x & (PXB-1);
    int ch  = blockIdx.x / PXB;

    // stage chunk params: CHUNK*8 = 1024 floats = 256 float4
    ((float4*)&sp[0][0])[tid] = ((const float4*)(params + ch*CHUNK*8))[tid];
    __syncthreads();

    int p = pb*256 + tid;
    float px = (float)(p & (WW-1));
    float py = (float)(p >> 7);

    float accv = 0.f;
    #pragma unroll 4
    for (int g = 0; g < CHUNK; ++g) {
        float4 v0 = *(const float4*)&sp[g][0];   // mux, muy, A, B
        float2 v1 = *(const float2*)&sp[g][4];   // C, c0
        float dx = px - v0.x;
        float dy = py - v0.y;
        float e = fmaf(v0.z*dx, dx, fmaf(v0.w*dx, dy, fmaf(v1.x*dy, dy, v1.y)));
        accv += EXP2F(e);
    }
    atomicAdd(&acc[p], accv);
}

__global__ __launch_bounds__(256) void blockmax_kernel(
    const float* __restrict__ acc, float* __restrict__ bmax)
{
    int p = blockIdx.x*256 + threadIdx.x;
    float v = acc[p];
    #pragma unroll
    for (int off = 32; off > 0; off >>= 1)
        v = fmaxf(v, __shfl_xor(v, off));
    __shared__ float sm[4];
    if ((threadIdx.x & 63) == 0) sm[threadIdx.x >> 6] = v;
    __syncthreads();
    if (threadIdx.x == 0)
        bmax[blockIdx.x] = fmaxf(fmaxf(sm[0], sm[1]), fmaxf(sm[2], sm[3]));
}

__global__ __launch_bounds__(256) void norm_kernel(
    const float* __restrict__ acc, const float* __restrict__ bmax,
    float* __restrict__ out)
{
    float m = 0.f;
    for (int i = 0; i < PXB; ++i) m = fmaxf(m, bmax[i]);
    m = fmaxf(m, EPSF);
    int p = blockIdx.x*256 + threadIdx.x;
    out[p] = acc[p] / m;
}

extern "C" void kernel_launch(void* const* d_in, const int* in_sizes, int n_in,
                              void* d_out, int out_size, void* d_ws, size_t ws_size,
                              hipStream_t stream) {
    const float* means      = (const float*)d_in[0];
    const float* raw_scales = (const float*)d_in[1];
    const float* rotors     = (const float*)d_in[2];
    const float* t          = (const float*)d_in[3];
    const float* angle      = (const float*)d_in[4];
    float* out = (float*)d_out;

    float* params = (float*)d_ws;          // NG*8 floats   = 128 KiB
    float* acc    = params + NG*8;         // NPIX floats   =  64 KiB
    float* bmax   = acc + NPIX;            // PXB floats    = 256 B

    hipMemsetAsync(acc, 0, NPIX*sizeof(float), stream);
    prep_kernel<<<NG/256, 256, 0, stream>>>(means, raw_scales, rotors, t, angle, params);
    accum_kernel<<<PXB*NCH, 256, 0, stream>>>(params, acc);
    blockmax_kernel<<<PXB, 256, 0, stream>>>(acc, bmax);
    norm_kernel<<<PXB, 256, 0, stream>>>(acc, bmax, out);
}